// Round 2
// baseline (223.276 us; speedup 1.0000x reference)
//
#include <hip/hip_runtime.h>

// HarmonicMixing closed form per row of D=1024 channels (all gathers read the
// ORIGINAL x):
//   out[j] = x[j]
//          + sum_{o=1..3, s=2^o} ( [j%s==0] * sig(uw[o]) * x[j/s]        (up)
//                                 + [1<=j<D/s] * sig(dw[o]) * W_s[j] )   (down)
// where W_s[j] = sum(x[j*s .. j*s+s-1]) — a hierarchy of pair sums:
//   S1[j]=x[2j]+x[2j+1], S2=pairsum(S1), S3=pairsum(S2); W_2=S1, W_4=S2, W_8=S3.
//
// R1 lesson: strided LDS window reads -> 16/32-way bank conflicts; fixed by
//   register-side pair sums + stride-1 LDS layout (all kept here verbatim).
// R3: (a) 4 rows per block: 4 independent float4 loads in flight per thread
//   (MLP 1 -> 4), ONE __syncthreads per 16 KB instead of per 4 KB.
//   (b) Nontemporal load/store: 268 MB/iter working set > 256 MB L3, so
//   caching is pure thrash; reuse is entirely register/LDS side.
// R4: compile fix — __builtin_nontemporal_* requires a NATIVE vector type,
//   not HIP_vector_type<float,4>; use ext_vector_type(4) float.

constexpr int D = 1024;

using f4 = __attribute__((ext_vector_type(4))) float;  // native vec: ok for nontemporal builtins

template <int R>
__global__ __launch_bounds__(256, 7) void harmonic_kernel(
    const float* __restrict__ x,
    const float* __restrict__ uwp,
    const float* __restrict__ dwp,
    float* __restrict__ out)
{
    __shared__ float rowlo[R][512];  // x[0..511] — only lower half is gathered by up-terms
    __shared__ float S1[R][512];
    __shared__ float S2[R][256];
    __shared__ float S3[R][128];

    const int t = threadIdx.x;
    const long long base = (long long)blockIdx.x * R * D;

    const float uw0 = 1.f / (1.f + __expf(-uwp[0]));
    const float uw1 = 1.f / (1.f + __expf(-uwp[1]));
    const float uw2 = 1.f / (1.f + __expf(-uwp[2]));
    const float dw0 = 1.f / (1.f + __expf(-dwp[0]));
    const float dw1 = 1.f / (1.f + __expf(-dwp[1]));
    const float dw2 = 1.f / (1.f + __expf(-dwp[2]));

    const int j0 = t * 4;  // this thread's 4 consecutive channels (per row)

    // ---- issue all R independent loads first: 4x memory-level parallelism ----
    f4 v[R];
#pragma unroll
    for (int r = 0; r < R; ++r) {
        v[r] = __builtin_nontemporal_load(
            reinterpret_cast<const f4*>(x + base + (long long)r * D + j0));
    }

    // ---- register-side pair-sum hierarchy + conflict-free LDS staging ----
#pragma unroll
    for (int r = 0; r < R; ++r) {
        const float s1a = v[r].x + v[r].y;               // S1[2t]
        const float s1b = v[r].z + v[r].w;               // S1[2t+1]
        const float s2  = s1a + s1b;                     // S2[t]
        const float s3  = s2 + __shfl_xor(s2, 1);        // S3[t>>1] (valid on even t)

        if (t < 128) *reinterpret_cast<f4*>(&rowlo[r][j0]) = v[r];  // stride-1 b128
        *reinterpret_cast<float2*>(&S1[r][2 * t]) = make_float2(s1a, s1b); // b64
        S2[r][t] = s2;                                   // stride-1 b32
        if ((t & 1) == 0) S3[r][t >> 1] = s3;            // 32 lanes -> 32 banks, free
    }
    __syncthreads();  // ONE barrier for all R rows

#pragma unroll
    for (int r = 0; r < R; ++r) {
        f4 o = v[r];

        // --- up: out[j] += uw_o * x[j >> o] for j % 2^o == 0 ---
        const float2 u01 = *reinterpret_cast<const float2*>(&rowlo[r][2 * t]);
        o.x += uw0 * u01.x;                  // j=4t   : x[2t]
        o.z += uw0 * u01.y;                  // j=4t+2 : x[2t+1]
        o.x += uw1 * rowlo[r][t];            // j%4==0 : x[t]
        if ((t & 1) == 0) o.x += uw2 * rowlo[r][t >> 1];  // j%8==0 : x[t/2]

        // --- down: out[j] += dw_o * S_o[j], 1 <= j < D/2^o --- (all stride-1 b128)
        if (t < 128) {
            const f4 a = *reinterpret_cast<const f4*>(&S1[r][j0]);
            if (t > 0) o.x += dw0 * a.x;     // j=0 excluded
            o.y += dw0 * a.y;
            o.z += dw0 * a.z;
            o.w += dw0 * a.w;
            if (t < 64) {
                const f4 b = *reinterpret_cast<const f4*>(&S2[r][j0]);
                if (t > 0) o.x += dw1 * b.x;
                o.y += dw1 * b.y;
                o.z += dw1 * b.z;
                o.w += dw1 * b.w;
                if (t < 32) {
                    const f4 c = *reinterpret_cast<const f4*>(&S3[r][j0]);
                    if (t > 0) o.x += dw2 * c.x;
                    o.y += dw2 * c.y;
                    o.z += dw2 * c.z;
                    o.w += dw2 * c.w;
                }
            }
        }

        __builtin_nontemporal_store(
            o, reinterpret_cast<f4*>(out + base + (long long)r * D + j0));
    }
}

extern "C" void kernel_launch(void* const* d_in, const int* in_sizes, int n_in,
                              void* d_out, int out_size, void* d_ws, size_t ws_size,
                              hipStream_t stream) {
    const float* x   = (const float*)d_in[0];
    const float* uwp = (const float*)d_in[1];
    const float* dwp = (const float*)d_in[2];
    float* out = (float*)d_out;
    const int n_rows = in_sizes[0] / D;  // 8 * 4096 = 32768
    const int nb  = n_rows / 4;
    const int rem = n_rows % 4;
    if (nb)
        harmonic_kernel<4><<<nb, 256, 0, stream>>>(x, uwp, dwp, out);
    if (rem)  // tail (not hit for the benchmark shape; kept for correctness)
        harmonic_kernel<1><<<rem, 256, 0, stream>>>(
            x + (long long)nb * 4 * D, uwp, dwp, out + (long long)nb * 4 * D);
}